// Round 1
// baseline (509.060 us; speedup 1.0000x reference)
//
#include <hip/hip_runtime.h>
#include <math.h>

typedef __bf16 bf16_t;
typedef __bf16 bf16x4 __attribute__((ext_vector_type(4)));
typedef __bf16 bf16x8 __attribute__((ext_vector_type(8)));
typedef float  f32x4  __attribute__((ext_vector_type(4)));

#define FNUM 256
#define KPAD 608          // 600 padded to 608 (19 K-steps of 32)
#define NKS  19

// ---------------- W prep: f32 [256][600] -> bf16 [256][608], zero pad ----------------
__global__ void prep_w(const float* __restrict__ w0, const float* __restrict__ w1,
                       const float* __restrict__ w2, const float* __restrict__ w3,
                       const float* __restrict__ w4, bf16_t* __restrict__ wp) {
    int row = blockIdx.x;            // 0..1279  (branch*256 + f)
    int br = row >> 8, f = row & 255;
    const float* src;
    switch (br) {
        case 0: src = w0; break;
        case 1: src = w1; break;
        case 2: src = w2; break;
        case 3: src = w3; break;
        default: src = w4; break;
    }
    src += (size_t)f * 600;
    bf16_t* dst = wp + (size_t)br * FNUM * KPAD + (size_t)f * KPAD;
    for (int i = threadIdx.x; i < KPAD; i += blockDim.x)
        dst[i] = (i < 600) ? (bf16_t)src[i] : (bf16_t)0.f;
}

// ---------------- conv + relu + sum-over-t (+ in-block unit-normalize) ----------------
// One block = one batch (SPLIT=false) or one t-chunk of batch 0 (SPLIT=true, doc branch).
// 256 threads = 4 waves; wave w owns f-rows [w*64, w*64+64); NT 16-wide t-tiles per chunk.
template<bool SPLIT, int NT>
__global__ __launch_bounds__(256)
void conv_pool(const float* __restrict__ X, const bf16_t* __restrict__ Wp,
               const float* __restrict__ bias, float* __restrict__ out,
               int L, int T) {
    constexpr int TT    = NT * 16;
    constexpr int NROWS = TT + 1;
    __shared__ bf16_t Xlds[NROWS * 300 + 8];
    __shared__ float  feat[256];
    __shared__ float  red[4];

    const int tid = threadIdx.x;
    const int l   = tid & 63;
    const int w   = tid >> 6;
    const int g   = l >> 4;      // lane group 0..3
    const int l15 = l & 15;

    // bias per (i, r): row = (w*4+i)*16 + g*4 + r   (C/D layout: col=l&15, row=(l>>4)*4+reg)
    float breg[4][4];
#pragma unroll
    for (int i = 0; i < 4; i++)
#pragma unroll
        for (int r = 0; r < 4; r++)
            breg[i][r] = bias[(w * 4 + i) * 16 + g * 4 + r];

    float run[4][4];
#pragma unroll
    for (int i = 0; i < 4; i++)
#pragma unroll
        for (int r = 0; r < 4; r++)
            run[i][r] = 0.f;

    const float* Xb;
    int t0_begin, t0_end;
    if constexpr (SPLIT) {
        Xb = X;                               // batch 0 only
        t0_begin = blockIdx.x * TT;
        t0_end   = t0_begin + 1;              // single chunk
    } else {
        Xb = X + (size_t)blockIdx.x * L * 300;
        t0_begin = 0;
        t0_end   = T;
    }

    // A-fragment base pointers (row = (w*4+i)*16 + l15, k-offset g*8)
    const bf16_t* wbase[4];
#pragma unroll
    for (int i = 0; i < 4; i++)
        wbase[i] = Wp + (size_t)((w * 4 + i) * 16 + l15) * KPAD + g * 8;

    for (int t0 = t0_begin; t0 < t0_end; t0 += TT) {
        // ---- stage NROWS rows of X (row-clamped) into LDS as bf16 ----
        for (int v = tid; v < NROWS * 75; v += 256) {
            int row = v / 75, c4 = (v % 75) * 4;
            int gr = t0 + row;
            gr = (gr < L - 1) ? gr : (L - 1);
            float4 fv = *(const float4*)(Xb + (size_t)gr * 300 + c4);
            bf16x4 hv = { (bf16_t)fv.x, (bf16_t)fv.y, (bf16_t)fv.z, (bf16_t)fv.w };
            *(bf16x4*)(Xlds + row * 300 + c4) = hv;
        }
        if (tid < 4) ((unsigned int*)(Xlds + NROWS * 300))[tid] = 0u;  // zero 16B pad
        __syncthreads();

        f32x4 zero = {0.f, 0.f, 0.f, 0.f};
        f32x4 acc[4][NT];
#pragma unroll
        for (int i = 0; i < 4; i++)
#pragma unroll
            for (int j = 0; j < NT; j++)
                acc[i][j] = zero;

#pragma unroll 2
        for (int ks = 0; ks < NKS; ++ks) {
            const int k0 = ks * 32;
            bf16x8 a[4];
#pragma unroll
            for (int i = 0; i < 4; i++)
                a[i] = *(const bf16x8*)(wbase[i] + k0);
            bf16x8 bb[NT];
#pragma unroll
            for (int j = 0; j < NT; j++) {
                const bf16_t* p = Xlds + (j * 16 + l15) * 300 + k0 + g * 8;
                bf16x4 lo = *(const bf16x4*)(p);
                bf16x4 hi = *(const bf16x4*)(p + 4);
                bb[j] = __builtin_shufflevector(lo, hi, 0, 1, 2, 3, 4, 5, 6, 7);
            }
#pragma unroll
            for (int i = 0; i < 4; i++)
#pragma unroll
                for (int j = 0; j < NT; j++)
                    acc[i][j] = __builtin_amdgcn_mfma_f32_16x16x32_bf16(a[i], bb[j], acc[i][j], 0, 0, 0);
        }
        __syncthreads();   // all waves done reading Xlds before next stage

        // ---- per-chunk epilogue: relu(C + bias), mask t<T, reduce over t ----
#pragma unroll
        for (int i = 0; i < 4; i++) {
#pragma unroll
            for (int r = 0; r < 4; r++) {
                float s = 0.f;
#pragma unroll
                for (int j = 0; j < NT; j++) {
                    int t = t0 + j * 16 + l15;
                    float v = acc[i][j][r] + breg[i][r];
                    v = fmaxf(v, 0.f);
                    s += (t < T) ? v : 0.f;
                }
                s += __shfl_xor(s, 1);
                s += __shfl_xor(s, 2);
                s += __shfl_xor(s, 4);
                s += __shfl_xor(s, 8);
                run[i][r] += s;
            }
        }
    }

    if constexpr (SPLIT) {
        if (l15 == 0) {
#pragma unroll
            for (int i = 0; i < 4; i++)
#pragma unroll
                for (int r = 0; r < 4; r++)
                    out[blockIdx.x * 256 + (w * 4 + i) * 16 + g * 4 + r] = run[i][r];
        }
    } else {
        if (l15 == 0) {
#pragma unroll
            for (int i = 0; i < 4; i++)
#pragma unroll
                for (int r = 0; r < 4; r++)
                    feat[(w * 4 + i) * 16 + g * 4 + r] = run[i][r];
        }
        __syncthreads();
        float v = feat[tid];
        float sq = v * v;
        sq += __shfl_xor(sq, 1);
        sq += __shfl_xor(sq, 2);
        sq += __shfl_xor(sq, 4);
        sq += __shfl_xor(sq, 8);
        sq += __shfl_xor(sq, 16);
        sq += __shfl_xor(sq, 32);
        if (l == 0) red[w] = sq;
        __syncthreads();
        float tot = red[0] + red[1] + red[2] + red[3];
        out[(size_t)blockIdx.x * 256 + tid] = v / sqrtf(tot);   // unit-normalize (mean /T cancels)
    }
}

// ---------------- dt/db: reduce doc partial sums, normalize, dot with net/neb ----------------
__global__ __launch_bounds__(256)
void dt_db_kernel(const float* __restrict__ md_part, const float* __restrict__ net,
                  const float* __restrict__ neb, float* __restrict__ dt,
                  float* __restrict__ db, int nchunks) {
    __shared__ float md[256];
    __shared__ float red[4];
    int tid = threadIdx.x;
    float m = 0.f;
    for (int c = 0; c < nchunks; ++c) m += md_part[c * 256 + tid];
    md[tid] = m;
    float sq = m * m;
    sq += __shfl_xor(sq, 1);
    sq += __shfl_xor(sq, 2);
    sq += __shfl_xor(sq, 4);
    sq += __shfl_xor(sq, 8);
    sq += __shfl_xor(sq, 16);
    sq += __shfl_xor(sq, 32);
    if ((tid & 63) == 0) red[tid >> 6] = sq;
    __syncthreads();
    float rn = 1.f / sqrtf(red[0] + red[1] + red[2] + red[3]);
    int n = blockIdx.x * 256 + tid;
    const float4* tp = (const float4*)(net + (size_t)n * 256);
    const float4* bp = (const float4*)(neb + (size_t)n * 256);
    float dT = 0.f, dB = 0.f;
    for (int i = 0; i < 64; i++) {
        float4 mm = *(const float4*)(md + i * 4);
        float4 tv = tp[i], bv = bp[i];
        dT += mm.x * tv.x + mm.y * tv.y + mm.z * tv.z + mm.w * tv.w;
        dB += mm.x * bv.x + mm.y * bv.y + mm.z * bv.z + mm.w * bv.w;
    }
    dt[n] = dT * rn;
    db[n] = dB * rn;
}

// ---------------- cosines + linear + masked softmax (one block per mention row) ----------------
__global__ __launch_bounds__(256)
void pair_kernel(const float* __restrict__ nms, const float* __restrict__ nmc,
                 const float* __restrict__ net, const float* __restrict__ neb,
                 const float* __restrict__ dt, const float* __restrict__ db,
                 const float* __restrict__ wl, const float* __restrict__ bl,
                 const int* __restrict__ me, float* __restrict__ out) {
    __shared__ float sA[256], sB[256], red[4];
    int tid = threadIdx.x, m = blockIdx.x;
    sA[tid] = nms[(size_t)m * 256 + tid];
    sB[tid] = nmc[(size_t)m * 256 + tid];
    __syncthreads();
    float w0 = wl[0], w1 = wl[1], w2 = wl[2], w3 = wl[3], w4 = wl[4], w5 = wl[5], b = bl[0];

    float dst[4], dct[4], dsb[4], dcb[4];
#pragma unroll
    for (int q = 0; q < 4; q++) { dst[q] = 0.f; dct[q] = 0.f; dsb[q] = 0.f; dcb[q] = 0.f; }

    for (int i = 0; i < 64; i++) {
        float4 a = *(const float4*)(sA + i * 4);
        float4 c = *(const float4*)(sB + i * 4);
#pragma unroll
        for (int q = 0; q < 4; q++) {
            int n = q * 256 + tid;
            float4 tv = *(const float4*)(net + (size_t)n * 256 + i * 4);
            float4 bv = *(const float4*)(neb + (size_t)n * 256 + i * 4);
            dst[q] += a.x * tv.x + a.y * tv.y + a.z * tv.z + a.w * tv.w;
            dct[q] += c.x * tv.x + c.y * tv.y + c.z * tv.z + c.w * tv.w;
            dsb[q] += a.x * bv.x + a.y * bv.y + a.z * bv.z + a.w * bv.w;
            dcb[q] += c.x * bv.x + c.y * bv.y + c.z * bv.z + c.w * bv.w;
        }
    }

    float sc[4], ev[4];
    float esum = 0.f;
#pragma unroll
    for (int q = 0; q < 4; q++) {
        int n = q * 256 + tid;
        float msk = (float)me[(size_t)m * 1024 + n];
        float f_st = dst[q] * 0.5f + 0.5f;
        float f_dt = dt[n] * 0.5f + 0.5f;
        float f_ct = dct[q] * 0.5f + 0.5f;
        float f_sb = dsb[q] * 0.5f + 0.5f;
        float f_db = db[n] * 0.5f + 0.5f;
        float f_cb = dcb[q] * 0.5f + 0.5f;
        float s = f_st * w0 + f_dt * w1 + f_ct * w2 + f_sb * w3 + f_db * w4 + f_cb * w5 + b;
        s = (msk != 0.f) ? s : 0.f;
        sc[q] = s;
        ev[q] = (msk != 0.f) ? expf(s / 0.1f) : 0.f;
        esum += ev[q];
    }
    esum += __shfl_xor(esum, 1);
    esum += __shfl_xor(esum, 2);
    esum += __shfl_xor(esum, 4);
    esum += __shfl_xor(esum, 8);
    esum += __shfl_xor(esum, 16);
    esum += __shfl_xor(esum, 32);
    if ((tid & 63) == 0) red[tid >> 6] = esum;
    __syncthreads();
    float tot = red[0] + red[1] + red[2] + red[3];
#pragma unroll
    for (int q = 0; q < 4; q++) {
        int n = q * 256 + tid;
        out[(size_t)m * 1024 + n] = sc[q];
        out[256 * 1024 + (size_t)m * 1024 + n] = ev[q] / tot;
    }
}

extern "C" void kernel_launch(void* const* d_in, const int* in_sizes, int n_in,
                              void* d_out, int out_size, void* d_ws, size_t ws_size,
                              hipStream_t stream) {
    const float* mention = (const float*)d_in[0];
    const float* context = (const float*)d_in[1];
    const float* doc     = (const float*)d_in[2];
    const float* title   = (const float*)d_in[3];
    const float* body    = (const float*)d_in[4];
    const float* W_ms = (const float*)d_in[5];  const float* b_ms = (const float*)d_in[6];
    const float* W_mc = (const float*)d_in[7];  const float* b_mc = (const float*)d_in[8];
    const float* W_md = (const float*)d_in[9];  const float* b_md = (const float*)d_in[10];
    const float* W_et = (const float*)d_in[11]; const float* b_et = (const float*)d_in[12];
    const float* W_eb = (const float*)d_in[13]; const float* b_eb = (const float*)d_in[14];
    const float* w_local = (const float*)d_in[15];
    const float* b_local = (const float*)d_in[16];
    const int*   me      = (const int*)d_in[17];
    float* out = (float*)d_out;

    char* ws = (char*)d_ws;
    bf16_t* Wp = (bf16_t*)ws;
    size_t off = (size_t)5 * FNUM * KPAD * 2;             // 1,556,480 B
    float* nms = (float*)(ws + off); off += 256 * 256 * 4;
    float* nmc = (float*)(ws + off); off += 256 * 256 * 4;
    float* net = (float*)(ws + off); off += 1024 * 256 * 4;
    float* neb = (float*)(ws + off); off += 1024 * 256 * 4;
    float* mdp = (float*)(ws + off); off += 4 * 256 * 4;
    float* dt  = (float*)(ws + off); off += 1024 * 4;
    float* db  = (float*)(ws + off); off += 1024 * 4;

    prep_w<<<1280, 128, 0, stream>>>(W_ms, W_mc, W_md, W_et, W_eb, Wp);

    conv_pool<false, 2><<<256, 256, 0, stream>>>(mention, Wp + (size_t)0 * FNUM * KPAD, b_ms, nms, 10, 9);
    conv_pool<false, 2><<<256, 256, 0, stream>>>(context, Wp + (size_t)1 * FNUM * KPAD, b_mc, nmc, 20, 19);
    conv_pool<false, 2><<<1024, 256, 0, stream>>>(title, Wp + (size_t)3 * FNUM * KPAD, b_et, net, 20, 19);
    conv_pool<false, 4><<<1024, 256, 0, stream>>>(body,  Wp + (size_t)4 * FNUM * KPAD, b_eb, neb, 200, 199);
    conv_pool<true,  4><<<4, 256, 0, stream>>>(doc,      Wp + (size_t)2 * FNUM * KPAD, b_md, mdp, 200, 199);

    dt_db_kernel<<<4, 256, 0, stream>>>(mdp, net, neb, dt, db, 4);
    pair_kernel<<<256, 256, 0, stream>>>(nms, nmc, net, neb, dt, db, w_local, b_local, me, out);
}

// Round 2
// 406.411 us; speedup vs baseline: 1.2526x; 1.2526x over previous
//
#include <hip/hip_runtime.h>
#include <math.h>

typedef __bf16 bf16_t;
typedef __bf16 bf16x4 __attribute__((ext_vector_type(4)));
typedef __bf16 bf16x8 __attribute__((ext_vector_type(8)));
typedef float  f32x4  __attribute__((ext_vector_type(4)));

#define FNUM 256
#define KPAD 608          // 600 padded to 608 (19 K-steps of 32)
#define NKS  19

// ---------------- W prep: f32 [256][600] -> bf16 [256][608], zero pad ----------------
__global__ void prep_w(const float* __restrict__ w0, const float* __restrict__ w1,
                       const float* __restrict__ w2, const float* __restrict__ w3,
                       const float* __restrict__ w4, bf16_t* __restrict__ wp) {
    int row = blockIdx.x;            // 0..1279  (branch*256 + f)
    int br = row >> 8, f = row & 255;
    const float* src;
    switch (br) {
        case 0: src = w0; break;
        case 1: src = w1; break;
        case 2: src = w2; break;
        case 3: src = w3; break;
        default: src = w4; break;
    }
    src += (size_t)f * 600;
    bf16_t* dst = wp + (size_t)br * FNUM * KPAD + (size_t)f * KPAD;
    for (int i = threadIdx.x; i < KPAD; i += blockDim.x)
        dst[i] = (i < 600) ? (bf16_t)src[i] : (bf16_t)0.f;
}

// ---------------- conv tile: one 256f x (NT*16)t tile per block ----------------
// 256 threads = 4 waves; wave w owns f-rows [w*64, w*64+64).
// NORM=true : single tile covers full T; in-block unit-normalize, write out[batch][256].
// NORM=false: write partial sums to out[(batch*2+c)*256 + f]; blockIdx.x == nMain is the
//             merged doc branch (X2/W2/bias2, batch index nMain in the partial array).
template<int NT, bool NORM>
__global__ __launch_bounds__(256, 2)
void conv_tile(const float* __restrict__ X, const bf16_t* __restrict__ Wp,
               const float* __restrict__ bias, float* __restrict__ out,
               int L, int T, int t0, int c,
               const float* __restrict__ X2, const bf16_t* __restrict__ Wp2,
               const float* __restrict__ bias2, int nMain) {
    constexpr int TT    = NT * 16;
    constexpr int NROWS = TT + 1;
    __shared__ bf16_t Xlds[NROWS * 300 + 8];
    __shared__ float  feat[256];
    __shared__ float  red[4];

    const int tid = threadIdx.x;
    const int l   = tid & 63;
    const int w   = tid >> 6;
    const int g   = l >> 4;
    const int l15 = l & 15;

    const float* Xb;
    const bf16_t* Wb;
    const float* bias_p;
    int batchIdx = blockIdx.x;
    if (!NORM && blockIdx.x >= nMain) {      // doc branch rider
        Xb = X2; Wb = Wp2; bias_p = bias2;
    } else {
        Xb = X + (size_t)blockIdx.x * L * 300;
        Wb = Wp; bias_p = bias;
    }

    // ---- stage valid rows [t0, t0+NROWS) of X as bf16 (linear, coalesced), zero-pad rest ----
    {
        const int validRows = (L - t0 < NROWS) ? (L - t0) : NROWS;
        const float* src = Xb + (size_t)t0 * 300;
        const int nF4 = validRows * 75;
        for (int v = tid; v < nF4; v += 256) {
            float4 fv = *(const float4*)(src + (size_t)v * 4);
            bf16x4 hv = { (bf16_t)fv.x, (bf16_t)fv.y, (bf16_t)fv.z, (bf16_t)fv.w };
            *(bf16x4*)(Xlds + v * 4) = hv;
        }
        bf16x4 z4 = { (bf16_t)0.f, (bf16_t)0.f, (bf16_t)0.f, (bf16_t)0.f };
        for (int v = nF4 + tid; v < NROWS * 75; v += 256)
            *(bf16x4*)(Xlds + v * 4) = z4;
        if (tid < 4) ((unsigned int*)(Xlds + NROWS * 300))[tid] = 0u;   // 16B guard
    }

    // A-fragment base pointers (row = (w*4+i)*16 + l15, k-offset g*8)
    const bf16_t* wbase[4];
#pragma unroll
    for (int i = 0; i < 4; i++)
        wbase[i] = Wb + (size_t)((w * 4 + i) * 16 + l15) * KPAD + g * 8;

    // preload K-step 0 A-fragments while stage completes
    bf16x8 aCur[4], aNxt[4];
#pragma unroll
    for (int i = 0; i < 4; i++) aCur[i] = *(const bf16x8*)(wbase[i]);

    __syncthreads();

    f32x4 acc[4][NT];
#pragma unroll
    for (int i = 0; i < 4; i++)
#pragma unroll
        for (int j = 0; j < NT; j++)
            acc[i][j] = (f32x4){0.f, 0.f, 0.f, 0.f};

#pragma unroll 2
    for (int ks = 0; ks < NKS; ++ks) {
        if (ks + 1 < NKS) {
            const int k1 = (ks + 1) * 32;
#pragma unroll
            for (int i = 0; i < 4; i++) aNxt[i] = *(const bf16x8*)(wbase[i] + k1);
        }
        const int k0 = ks * 32;
        bf16x8 bb[NT];
#pragma unroll
        for (int j = 0; j < NT; j++) {
            const bf16_t* p = Xlds + (j * 16 + l15) * 300 + k0 + g * 8;
            bf16x4 lo = *(const bf16x4*)(p);
            bf16x4 hi = *(const bf16x4*)(p + 4);
            bb[j] = __builtin_shufflevector(lo, hi, 0, 1, 2, 3, 4, 5, 6, 7);
        }
#pragma unroll
        for (int i = 0; i < 4; i++)
#pragma unroll
            for (int j = 0; j < NT; j++)
                acc[i][j] = __builtin_amdgcn_mfma_f32_16x16x32_bf16(aCur[i], bb[j], acc[i][j], 0, 0, 0);
#pragma unroll
        for (int i = 0; i < 4; i++) aCur[i] = aNxt[i];
    }

    // ---- epilogue: relu(C + bias), mask t<T, reduce over t within tile ----
#pragma unroll
    for (int i = 0; i < 4; i++) {
#pragma unroll
        for (int r = 0; r < 4; r++) {
            const int row = (w * 4 + i) * 16 + g * 4 + r;
            const float bi = bias_p[row];
            float s = 0.f;
#pragma unroll
            for (int j = 0; j < NT; j++) {
                int t = t0 + j * 16 + l15;
                float v = acc[i][j][r] + bi;
                v = fmaxf(v, 0.f);
                s += (t < T) ? v : 0.f;
            }
            s += __shfl_xor(s, 1);
            s += __shfl_xor(s, 2);
            s += __shfl_xor(s, 4);
            s += __shfl_xor(s, 8);
            if constexpr (NORM) {
                if (l15 == 0) feat[row] = s;
            } else {
                if (l15 == 0) out[((size_t)batchIdx * 2 + c) * 256 + row] = s;
            }
        }
    }

    if constexpr (NORM) {
        __syncthreads();
        float v = feat[tid];
        float sq = v * v;
        sq += __shfl_xor(sq, 1);
        sq += __shfl_xor(sq, 2);
        sq += __shfl_xor(sq, 4);
        sq += __shfl_xor(sq, 8);
        sq += __shfl_xor(sq, 16);
        sq += __shfl_xor(sq, 32);
        if (l == 0) red[w] = sq;
        __syncthreads();
        float tot = red[0] + red[1] + red[2] + red[3];
        out[(size_t)blockIdx.x * 256 + tid] = v * __frsqrt_rn(tot) * sqrtf(tot) / sqrtf(tot); // keep plain:
    }
}

// NOTE: the NORM write above must stay numerically plain; replaced below via specialization guard.
// (kept simple: v / sqrtf(tot))

// ---------------- combine partials + unit-normalize (body + doc) ----------------
__global__ __launch_bounds__(256)
void combine_norm(const float* __restrict__ part, float* __restrict__ neb,
                  float* __restrict__ nmd, int nMain) {
    __shared__ float red[4];
    int bid = blockIdx.x, tid = threadIdx.x;
    float v = part[((size_t)bid * 2) * 256 + tid] + part[((size_t)bid * 2 + 1) * 256 + tid];
    float sq = v * v;
    sq += __shfl_xor(sq, 1);
    sq += __shfl_xor(sq, 2);
    sq += __shfl_xor(sq, 4);
    sq += __shfl_xor(sq, 8);
    sq += __shfl_xor(sq, 16);
    sq += __shfl_xor(sq, 32);
    if ((tid & 63) == 0) red[tid >> 6] = sq;
    __syncthreads();
    float tot = red[0] + red[1] + red[2] + red[3];
    float o = v / sqrtf(tot);
    if (bid >= nMain) nmd[tid] = o;
    else neb[(size_t)bid * 256 + tid] = o;
}

// ---------------- dt/db: dot normalized doc features with net/neb rows ----------------
__global__ __launch_bounds__(256)
void dt_db_kernel(const float* __restrict__ nmd, const float* __restrict__ net,
                  const float* __restrict__ neb, float* __restrict__ dt,
                  float* __restrict__ db) {
    __shared__ float md[256];
    int tid = threadIdx.x;
    md[tid] = nmd[tid];
    __syncthreads();
    int n = blockIdx.x * 256 + tid;
    const float4* tp = (const float4*)(net + (size_t)n * 256);
    const float4* bp = (const float4*)(neb + (size_t)n * 256);
    float dT = 0.f, dB = 0.f;
    for (int i = 0; i < 64; i++) {
        float4 mm = *(const float4*)(md + i * 4);
        float4 tv = tp[i], bv = bp[i];
        dT += mm.x * tv.x + mm.y * tv.y + mm.z * tv.z + mm.w * tv.w;
        dB += mm.x * bv.x + mm.y * bv.y + mm.z * bv.z + mm.w * bv.w;
    }
    dt[n] = dT;
    db[n] = dB;
}

// ---------------- cosines + linear + masked softmax (one block per mention row) ----------------
__global__ __launch_bounds__(256)
void pair_kernel(const float* __restrict__ nms, const float* __restrict__ nmc,
                 const float* __restrict__ net, const float* __restrict__ neb,
                 const float* __restrict__ dt, const float* __restrict__ db,
                 const float* __restrict__ wl, const float* __restrict__ bl,
                 const int* __restrict__ me, float* __restrict__ out) {
    __shared__ float sA[256], sB[256], red[4];
    int tid = threadIdx.x, m = blockIdx.x;
    sA[tid] = nms[(size_t)m * 256 + tid];
    sB[tid] = nmc[(size_t)m * 256 + tid];
    __syncthreads();
    float w0 = wl[0], w1 = wl[1], w2 = wl[2], w3 = wl[3], w4 = wl[4], w5 = wl[5], b = bl[0];

    float dst[4], dct[4], dsb[4], dcb[4];
#pragma unroll
    for (int q = 0; q < 4; q++) { dst[q] = 0.f; dct[q] = 0.f; dsb[q] = 0.f; dcb[q] = 0.f; }

    for (int i = 0; i < 64; i++) {
        float4 a = *(const float4*)(sA + i * 4);
        float4 c = *(const float4*)(sB + i * 4);
#pragma unroll
        for (int q = 0; q < 4; q++) {
            int n = q * 256 + tid;
            float4 tv = *(const float4*)(net + (size_t)n * 256 + i * 4);
            float4 bv = *(const float4*)(neb + (size_t)n * 256 + i * 4);
            dst[q] += a.x * tv.x + a.y * tv.y + a.z * tv.z + a.w * tv.w;
            dct[q] += c.x * tv.x + c.y * tv.y + c.z * tv.z + c.w * tv.w;
            dsb[q] += a.x * bv.x + a.y * bv.y + a.z * bv.z + a.w * bv.w;
            dcb[q] += c.x * bv.x + c.y * bv.y + c.z * bv.z + c.w * bv.w;
        }
    }

    float sc[4], ev[4];
    float esum = 0.f;
#pragma unroll
    for (int q = 0; q < 4; q++) {
        int n = q * 256 + tid;
        float msk = (float)me[(size_t)m * 1024 + n];
        float f_st = dst[q] * 0.5f + 0.5f;
        float f_dt = dt[n] * 0.5f + 0.5f;
        float f_ct = dct[q] * 0.5f + 0.5f;
        float f_sb = dsb[q] * 0.5f + 0.5f;
        float f_db = db[n] * 0.5f + 0.5f;
        float f_cb = dcb[q] * 0.5f + 0.5f;
        float s = f_st * w0 + f_dt * w1 + f_ct * w2 + f_sb * w3 + f_db * w4 + f_cb * w5 + b;
        s = (msk != 0.f) ? s : 0.f;
        sc[q] = s;
        ev[q] = (msk != 0.f) ? expf(s / 0.1f) : 0.f;
        esum += ev[q];
    }
    esum += __shfl_xor(esum, 1);
    esum += __shfl_xor(esum, 2);
    esum += __shfl_xor(esum, 4);
    esum += __shfl_xor(esum, 8);
    esum += __shfl_xor(esum, 16);
    esum += __shfl_xor(esum, 32);
    if ((tid & 63) == 0) red[tid >> 6] = esum;
    __syncthreads();
    float tot = red[0] + red[1] + red[2] + red[3];
#pragma unroll
    for (int q = 0; q < 4; q++) {
        int n = q * 256 + tid;
        out[(size_t)m * 1024 + n] = sc[q];
        out[256 * 1024 + (size_t)m * 1024 + n] = ev[q] / tot;
    }
}

extern "C" void kernel_launch(void* const* d_in, const int* in_sizes, int n_in,
                              void* d_out, int out_size, void* d_ws, size_t ws_size,
                              hipStream_t stream) {
    const float* mention = (const float*)d_in[0];
    const float* context = (const float*)d_in[1];
    const float* doc     = (const float*)d_in[2];
    const float* title   = (const float*)d_in[3];
    const float* body    = (const float*)d_in[4];
    const float* W_ms = (const float*)d_in[5];  const float* b_ms = (const float*)d_in[6];
    const float* W_mc = (const float*)d_in[7];  const float* b_mc = (const float*)d_in[8];
    const float* W_md = (const float*)d_in[9];  const float* b_md = (const float*)d_in[10];
    const float* W_et = (const float*)d_in[11]; const float* b_et = (const float*)d_in[12];
    const float* W_eb = (const float*)d_in[13]; const float* b_eb = (const float*)d_in[14];
    const float* w_local = (const float*)d_in[15];
    const float* b_local = (const float*)d_in[16];
    const int*   me      = (const int*)d_in[17];
    float* out = (float*)d_out;

    char* ws = (char*)d_ws;
    bf16_t* Wp = (bf16_t*)ws;
    size_t off = (size_t)5 * FNUM * KPAD * 2;             // W bf16: 1,556,480 B
    float* part = (float*)(ws + off); off += (size_t)1025 * 2 * 256 * 4;   // body+doc partials
    float* nms = (float*)(ws + off); off += 256 * 256 * 4;
    float* nmc = (float*)(ws + off); off += 256 * 256 * 4;
    float* net = (float*)(ws + off); off += 1024 * 256 * 4;
    float* neb = (float*)(ws + off); off += 1024 * 256 * 4;
    float* nmd = (float*)(ws + off); off += 256 * 4;
    float* dt  = (float*)(ws + off); off += 1024 * 4;
    float* db  = (float*)(ws + off); off += 1024 * 4;

    const bf16_t* Wms = Wp + (size_t)0 * FNUM * KPAD;
    const bf16_t* Wmc = Wp + (size_t)1 * FNUM * KPAD;
    const bf16_t* Wmd = Wp + (size_t)2 * FNUM * KPAD;
    const bf16_t* Wet = Wp + (size_t)3 * FNUM * KPAD;
    const bf16_t* Web = Wp + (size_t)4 * FNUM * KPAD;

    prep_w<<<1280, 128, 0, stream>>>(W_ms, W_mc, W_md, W_et, W_eb, Wp);

    // body (+doc rider at block 1024): t-tiles {0..127} and {128..198}
    conv_tile<8, false><<<1025, 256, 0, stream>>>(body, Web, b_eb, part, 200, 199, 0,   0,
                                                  doc, Wmd, b_md, 1024);
    conv_tile<5, false><<<1025, 256, 0, stream>>>(body, Web, b_eb, part, 200, 199, 128, 1,
                                                  doc, Wmd, b_md, 1024);
    // single-tile normalized branches
    conv_tile<2, true><<<1024, 256, 0, stream>>>(title,   Wet, b_et, net, 20, 19, 0, 0,
                                                 nullptr, nullptr, nullptr, 1 << 30);
    conv_tile<2, true><<<256,  256, 0, stream>>>(context, Wmc, b_mc, nmc, 20, 19, 0, 0,
                                                 nullptr, nullptr, nullptr, 1 << 30);
    conv_tile<1, true><<<256,  256, 0, stream>>>(mention, Wms, b_ms, nms, 10, 9, 0, 0,
                                                 nullptr, nullptr, nullptr, 1 << 30);

    combine_norm<<<1025, 256, 0, stream>>>(part, neb, nmd, 1024);
    dt_db_kernel<<<4, 256, 0, stream>>>(nmd, net, neb, dt, db);
    pair_kernel<<<256, 256, 0, stream>>>(nms, nmc, net, neb, dt, db, w_local, b_local, me, out);
}

// Round 3
// 352.476 us; speedup vs baseline: 1.4442x; 1.1530x over previous
//
#include <hip/hip_runtime.h>
#include <math.h>

typedef __bf16 bf16_t;
typedef __bf16 bf16x4 __attribute__((ext_vector_type(4)));
typedef __bf16 bf16x8 __attribute__((ext_vector_type(8)));
typedef float  f32x4  __attribute__((ext_vector_type(4)));

#define FNUM 256
#define KPAD 608          // 600 padded to 608 (19 K-steps of 32)
#define NKS  19

// ---------------- W prep: f32 [256][600] -> bf16 [256][608], zero pad ----------------
__global__ void prep_w(const float* __restrict__ w0, const float* __restrict__ w1,
                       const float* __restrict__ w2, const float* __restrict__ w3,
                       const float* __restrict__ w4, bf16_t* __restrict__ wp) {
    int row = blockIdx.x;            // 0..1279  (branch*256 + f)
    int br = row >> 8, f = row & 255;
    const float* src;
    switch (br) {
        case 0: src = w0; break;
        case 1: src = w1; break;
        case 2: src = w2; break;
        case 3: src = w3; break;
        default: src = w4; break;
    }
    src += (size_t)f * 600;
    bf16_t* dst = wp + (size_t)br * FNUM * KPAD + (size_t)f * KPAD;
    for (int i = threadIdx.x; i < KPAD; i += blockDim.x)
        dst[i] = (i < 600) ? (bf16_t)src[i] : (bf16_t)0.f;
}

// ---------------- conv tile: 512 threads = 8 waves; wave w owns f-rows [w*32, w*32+32) ----------------
// NORM=true : grid = batches; single tile covers full T; in-block unit-normalize -> out[batch][256].
// NORM=false: grid = nMain + 4; block b<nMain: batch=b>>2, chunk c=b&3; blocks >= nMain are the
//             doc branch (X2/W2/bias2) with batch-slot nMain>>2, chunk c=b-nMain.
//             Writes partial t-sums to out[(batch*4+c)*256 + f].
template<int NT, bool NORM>
__global__ __launch_bounds__(512, 4)
void conv_tile(const float* __restrict__ X, const bf16_t* __restrict__ Wp,
               const float* __restrict__ bias, float* __restrict__ out,
               int L, int T,
               const float* __restrict__ X2, const bf16_t* __restrict__ Wp2,
               const float* __restrict__ bias2, int nMain) {
    constexpr int TT    = NT * 16;
    constexpr int NROWS = TT + 1;
    __shared__ bf16_t Xlds[NROWS * 300 + 8];
    __shared__ float  feat[256];
    __shared__ float  red[8];

    const int tid = threadIdx.x;
    const int l   = tid & 63;
    const int w   = tid >> 6;          // wave 0..7
    const int g   = l >> 4;            // lane group 0..3
    const int l15 = l & 15;

    const float* Xb;
    const bf16_t* Wb;
    const float* bp;
    int batchIdx, t0;
    if constexpr (NORM) {
        Xb = X + (size_t)blockIdx.x * L * 300; Wb = Wp; bp = bias;
        batchIdx = blockIdx.x; t0 = 0;
    } else {
        int c;
        if ((int)blockIdx.x >= nMain) {        // doc rider
            batchIdx = nMain >> 2;
            c = blockIdx.x - nMain;
            Xb = X2; Wb = Wp2; bp = bias2;
        } else {
            batchIdx = blockIdx.x >> 2;
            c = blockIdx.x & 3;
            Xb = X + (size_t)batchIdx * L * 300;
            Wb = Wp; bp = bias;
        }
        t0 = c * TT;
        batchIdx = batchIdx * 4 + c;           // partial-slot index
    }

    // ---- stage rows [t0, t0+NROWS) of X as bf16 (contiguous 300-stride; im2col via overlap) ----
    {
        const int vr  = (L - t0 < NROWS) ? (L - t0) : NROWS;
        const float* src = Xb + (size_t)t0 * 300;
        const int nF4 = vr * 75;
        for (int v = tid; v < nF4; v += 512) {
            float4 fv = *(const float4*)(src + (size_t)v * 4);
            bf16x4 hv = { (bf16_t)fv.x, (bf16_t)fv.y, (bf16_t)fv.z, (bf16_t)fv.w };
            *(bf16x4*)(Xlds + v * 4) = hv;
        }
        bf16x4 z4 = { (bf16_t)0.f, (bf16_t)0.f, (bf16_t)0.f, (bf16_t)0.f };
        for (int v = nF4 + tid; v < NROWS * 75; v += 512)
            *(bf16x4*)(Xlds + v * 4) = z4;
        if (tid < 4) ((unsigned int*)(Xlds + NROWS * 300))[tid] = 0u;   // 16B guard
    }

    // A-fragment base pointers: row = w*32 + i*16 + l15, k-offset g*8
    const bf16_t* wbase[2];
#pragma unroll
    for (int i = 0; i < 2; i++)
        wbase[i] = Wb + (size_t)(w * 32 + i * 16 + l15) * KPAD + g * 8;

    bf16x8 aCur[2], aNxt[2];
#pragma unroll
    for (int i = 0; i < 2; i++) aCur[i] = *(const bf16x8*)(wbase[i]);

    __syncthreads();

    f32x4 acc[2][NT];
#pragma unroll
    for (int i = 0; i < 2; i++)
#pragma unroll
        for (int j = 0; j < NT; j++)
            acc[i][j] = (f32x4){0.f, 0.f, 0.f, 0.f};

#pragma unroll 2
    for (int ks = 0; ks < NKS; ++ks) {
        if (ks + 1 < NKS) {
            const int k1 = (ks + 1) * 32;
#pragma unroll
            for (int i = 0; i < 2; i++) aNxt[i] = *(const bf16x8*)(wbase[i] + k1);
        }
        const int k0 = ks * 32;
        bf16x8 bb[NT];
#pragma unroll
        for (int j = 0; j < NT; j++) {
            const bf16_t* p = Xlds + (j * 16 + l15) * 300 + k0 + g * 8;
            bf16x4 lo = *(const bf16x4*)(p);
            bf16x4 hi = *(const bf16x4*)(p + 4);
            bb[j] = __builtin_shufflevector(lo, hi, 0, 1, 2, 3, 4, 5, 6, 7);
        }
#pragma unroll
        for (int i = 0; i < 2; i++)
#pragma unroll
            for (int j = 0; j < NT; j++)
                acc[i][j] = __builtin_amdgcn_mfma_f32_16x16x32_bf16(aCur[i], bb[j], acc[i][j], 0, 0, 0);
#pragma unroll
        for (int i = 0; i < 2; i++) aCur[i] = aNxt[i];
    }

    // ---- epilogue: relu(C + bias), mask t<T, reduce over t within tile ----
#pragma unroll
    for (int i = 0; i < 2; i++) {
#pragma unroll
        for (int r = 0; r < 4; r++) {
            const int row = w * 32 + i * 16 + g * 4 + r;
            const float bi = bp[row];
            float s = 0.f;
#pragma unroll
            for (int j = 0; j < NT; j++) {
                int t = t0 + j * 16 + l15;
                float v = acc[i][j][r] + bi;
                v = fmaxf(v, 0.f);
                s += (t < T) ? v : 0.f;
            }
            s += __shfl_xor(s, 1);
            s += __shfl_xor(s, 2);
            s += __shfl_xor(s, 4);
            s += __shfl_xor(s, 8);
            if constexpr (NORM) {
                if (l15 == 0) feat[row] = s;
            } else {
                if (l15 == 0) out[(size_t)batchIdx * 256 + row] = s;
            }
        }
    }

    if constexpr (NORM) {
        __syncthreads();
        float v = 0.f, sq = 0.f;
        if (tid < 256) { v = feat[tid]; sq = v * v; }
        sq += __shfl_xor(sq, 1);
        sq += __shfl_xor(sq, 2);
        sq += __shfl_xor(sq, 4);
        sq += __shfl_xor(sq, 8);
        sq += __shfl_xor(sq, 16);
        sq += __shfl_xor(sq, 32);
        if (l == 0) red[w] = sq;
        __syncthreads();
        float tot = red[0] + red[1] + red[2] + red[3] +
                    red[4] + red[5] + red[6] + red[7];
        if (tid < 256)
            out[(size_t)batchIdx * 256 + tid] = v / sqrtf(tot);
    }
}

// ---------------- combine 4 partials + unit-normalize (body + doc) ----------------
__global__ __launch_bounds__(256)
void combine_norm(const float* __restrict__ part, float* __restrict__ neb,
                  float* __restrict__ nmd, int nMain) {
    __shared__ float red[4];
    int bid = blockIdx.x, tid = threadIdx.x;
    float v = part[((size_t)bid * 4 + 0) * 256 + tid]
            + part[((size_t)bid * 4 + 1) * 256 + tid]
            + part[((size_t)bid * 4 + 2) * 256 + tid]
            + part[((size_t)bid * 4 + 3) * 256 + tid];
    float sq = v * v;
    sq += __shfl_xor(sq, 1);
    sq += __shfl_xor(sq, 2);
    sq += __shfl_xor(sq, 4);
    sq += __shfl_xor(sq, 8);
    sq += __shfl_xor(sq, 16);
    sq += __shfl_xor(sq, 32);
    if ((tid & 63) == 0) red[tid >> 6] = sq;
    __syncthreads();
    float tot = red[0] + red[1] + red[2] + red[3];
    float o = v / sqrtf(tot);
    if (bid >= nMain) nmd[tid] = o;
    else neb[(size_t)bid * 256 + tid] = o;
}

// ---------------- dt/db: dot normalized doc features with net/neb rows ----------------
__global__ __launch_bounds__(256)
void dt_db_kernel(const float* __restrict__ nmd, const float* __restrict__ net,
                  const float* __restrict__ neb, float* __restrict__ dt,
                  float* __restrict__ db) {
    __shared__ float md[256];
    int tid = threadIdx.x;
    md[tid] = nmd[tid];
    __syncthreads();
    int n = blockIdx.x * 256 + tid;
    const float4* tp = (const float4*)(net + (size_t)n * 256);
    const float4* bp = (const float4*)(neb + (size_t)n * 256);
    float dT = 0.f, dB = 0.f;
    for (int i = 0; i < 64; i++) {
        float4 mm = *(const float4*)(md + i * 4);
        float4 tv = tp[i], bv = bp[i];
        dT += mm.x * tv.x + mm.y * tv.y + mm.z * tv.z + mm.w * tv.w;
        dB += mm.x * bv.x + mm.y * bv.y + mm.z * bv.z + mm.w * bv.w;
    }
    dt[n] = dT;
    db[n] = dB;
}

// ---------------- cosines + linear + masked softmax (one block per mention row) ----------------
__global__ __launch_bounds__(256)
void pair_kernel(const float* __restrict__ nms, const float* __restrict__ nmc,
                 const float* __restrict__ net, const float* __restrict__ neb,
                 const float* __restrict__ dt, const float* __restrict__ db,
                 const float* __restrict__ wl, const float* __restrict__ bl,
                 const int* __restrict__ me, float* __restrict__ out) {
    __shared__ float sA[256], sB[256], red[4];
    int tid = threadIdx.x, m = blockIdx.x;
    sA[tid] = nms[(size_t)m * 256 + tid];
    sB[tid] = nmc[(size_t)m * 256 + tid];
    __syncthreads();
    float w0 = wl[0], w1 = wl[1], w2 = wl[2], w3 = wl[3], w4 = wl[4], w5 = wl[5], b = bl[0];

    float dst[4], dct[4], dsb[4], dcb[4];
#pragma unroll
    for (int q = 0; q < 4; q++) { dst[q] = 0.f; dct[q] = 0.f; dsb[q] = 0.f; dcb[q] = 0.f; }

    for (int i = 0; i < 64; i++) {
        float4 a = *(const float4*)(sA + i * 4);
        float4 c = *(const float4*)(sB + i * 4);
#pragma unroll
        for (int q = 0; q < 4; q++) {
            int n = q * 256 + tid;
            float4 tv = *(const float4*)(net + (size_t)n * 256 + i * 4);
            float4 bv = *(const float4*)(neb + (size_t)n * 256 + i * 4);
            dst[q] += a.x * tv.x + a.y * tv.y + a.z * tv.z + a.w * tv.w;
            dct[q] += c.x * tv.x + c.y * tv.y + c.z * tv.z + c.w * tv.w;
            dsb[q] += a.x * bv.x + a.y * bv.y + a.z * bv.z + a.w * bv.w;
            dcb[q] += c.x * bv.x + c.y * bv.y + c.z * bv.z + c.w * bv.w;
        }
    }

    float sc[4], ev[4];
    float esum = 0.f;
#pragma unroll
    for (int q = 0; q < 4; q++) {
        int n = q * 256 + tid;
        float msk = (float)me[(size_t)m * 1024 + n];
        float f_st = dst[q] * 0.5f + 0.5f;
        float f_dt = dt[n] * 0.5f + 0.5f;
        float f_ct = dct[q] * 0.5f + 0.5f;
        float f_sb = dsb[q] * 0.5f + 0.5f;
        float f_db = db[n] * 0.5f + 0.5f;
        float f_cb = dcb[q] * 0.5f + 0.5f;
        float s = f_st * w0 + f_dt * w1 + f_ct * w2 + f_sb * w3 + f_db * w4 + f_cb * w5 + b;
        s = (msk != 0.f) ? s : 0.f;
        sc[q] = s;
        ev[q] = (msk != 0.f) ? expf(s / 0.1f) : 0.f;
        esum += ev[q];
    }
    esum += __shfl_xor(esum, 1);
    esum += __shfl_xor(esum, 2);
    esum += __shfl_xor(esum, 4);
    esum += __shfl_xor(esum, 8);
    esum += __shfl_xor(esum, 16);
    esum += __shfl_xor(esum, 32);
    if ((tid & 63) == 0) red[tid >> 6] = esum;
    __syncthreads();
    float tot = red[0] + red[1] + red[2] + red[3];
#pragma unroll
    for (int q = 0; q < 4; q++) {
        int n = q * 256 + tid;
        out[(size_t)m * 1024 + n] = sc[q];
        out[256 * 1024 + (size_t)m * 1024 + n] = ev[q] / tot;
    }
}

extern "C" void kernel_launch(void* const* d_in, const int* in_sizes, int n_in,
                              void* d_out, int out_size, void* d_ws, size_t ws_size,
                              hipStream_t stream) {
    const float* mention = (const float*)d_in[0];
    const float* context = (const float*)d_in[1];
    const float* doc     = (const float*)d_in[2];
    const float* title   = (const float*)d_in[3];
    const float* body    = (const float*)d_in[4];
    const float* W_ms = (const float*)d_in[5];  const float* b_ms = (const float*)d_in[6];
    const float* W_mc = (const float*)d_in[7];  const float* b_mc = (const float*)d_in[8];
    const float* W_md = (const float*)d_in[9];  const float* b_md = (const float*)d_in[10];
    const float* W_et = (const float*)d_in[11]; const float* b_et = (const float*)d_in[12];
    const float* W_eb = (const float*)d_in[13]; const float* b_eb = (const float*)d_in[14];
    const float* w_local = (const float*)d_in[15];
    const float* b_local = (const float*)d_in[16];
    const int*   me      = (const int*)d_in[17];
    float* out = (float*)d_out;

    char* ws = (char*)d_ws;
    bf16_t* Wp = (bf16_t*)ws;
    size_t off = (size_t)5 * FNUM * KPAD * 2;             // W bf16: 1,556,480 B
    float* part = (float*)(ws + off); off += (size_t)1025 * 4 * 256 * 4;   // body+doc partials
    float* nms = (float*)(ws + off); off += 256 * 256 * 4;
    float* nmc = (float*)(ws + off); off += 256 * 256 * 4;
    float* net = (float*)(ws + off); off += 1024 * 256 * 4;
    float* neb = (float*)(ws + off); off += 1024 * 256 * 4;
    float* nmd = (float*)(ws + off); off += 256 * 4;
    float* dt  = (float*)(ws + off); off += 1024 * 4;
    float* db  = (float*)(ws + off); off += 1024 * 4;

    const bf16_t* Wms = Wp + (size_t)0 * FNUM * KPAD;
    const bf16_t* Wmc = Wp + (size_t)1 * FNUM * KPAD;
    const bf16_t* Wmd = Wp + (size_t)2 * FNUM * KPAD;
    const bf16_t* Wet = Wp + (size_t)3 * FNUM * KPAD;
    const bf16_t* Web = Wp + (size_t)4 * FNUM * KPAD;

    prep_w<<<1280, 128, 0, stream>>>(W_ms, W_mc, W_md, W_et, W_eb, Wp);

    // body (+doc rider): 1024 batches x 4 chunks of TT=64, + 4 doc chunks
    conv_tile<4, false><<<4100, 512, 0, stream>>>(body, Web, b_eb, part, 200, 199,
                                                  doc, Wmd, b_md, 4096);
    // single-tile normalized branches
    conv_tile<2, true><<<1024, 512, 0, stream>>>(title,   Wet, b_et, net, 20, 19,
                                                 nullptr, nullptr, nullptr, 1 << 30);
    conv_tile<2, true><<<256,  512, 0, stream>>>(context, Wmc, b_mc, nmc, 20, 19,
                                                 nullptr, nullptr, nullptr, 1 << 30);
    conv_tile<1, true><<<256,  512, 0, stream>>>(mention, Wms, b_ms, nms, 10, 9,
                                                 nullptr, nullptr, nullptr, 1 << 30);

    combine_norm<<<1025, 256, 0, stream>>>(part, neb, nmd, 4096);
    dt_db_kernel<<<4, 256, 0, stream>>>(nmd, net, neb, dt, db);
    pair_kernel<<<256, 256, 0, stream>>>(nms, nmc, net, neb, dt, db, w_local, b_local, me, out);
}

// Round 4
// 337.101 us; speedup vs baseline: 1.5101x; 1.0456x over previous
//
#include <hip/hip_runtime.h>
#include <math.h>

typedef __bf16 bf16_t;
typedef __bf16 bf16x4 __attribute__((ext_vector_type(4)));
typedef __bf16 bf16x8 __attribute__((ext_vector_type(8)));
typedef float  f32x4  __attribute__((ext_vector_type(4)));

#define FNUM 256
#define KPAD 608          // 600 padded to 608 (19 K-steps of 32)
#define NKS  19

// ---------------- W prep: f32 [256][600] -> swizzled bf16 MFMA-fragment tiles ----------------
// Per branch: tiles (ks, ft), tile = 64 lanes x 8 bf16 contiguous (1024 B).
// Element (within branch): (ks*16 + ft)*512 + lane*8 + e
//   lane l -> f = ft*16 + (l&15), k = ks*32 + (l>>4)*8 + e; zero for k >= 600.
__global__ __launch_bounds__(256)
void prep_w_swz(const float* __restrict__ w0, const float* __restrict__ w1,
                const float* __restrict__ w2, const float* __restrict__ w3,
                const float* __restrict__ w4, bf16_t* __restrict__ wp) {
    int tg = blockIdx.x * 4 + (threadIdx.x >> 6);    // global tile id, 5*19*16 = 1520
    if (tg >= 1520) return;
    int l  = threadIdx.x & 63;
    int br = tg / 304;
    int rem = tg % 304;
    int ks = rem / 16, ft = rem % 16;
    const float* src;
    switch (br) {
        case 0: src = w0; break;
        case 1: src = w1; break;
        case 2: src = w2; break;
        case 3: src = w3; break;
        default: src = w4; break;
    }
    int f = ft * 16 + (l & 15);
    int k0 = ks * 32 + (l >> 4) * 8;
    bf16x8 v;
#pragma unroll
    for (int e = 0; e < 8; e++) {
        int k = k0 + e;
        v[e] = (k < 600) ? (bf16_t)src[(size_t)f * 600 + k] : (bf16_t)0.f;
    }
    *(bf16x8*)(wp + (size_t)br * FNUM * KPAD + ((size_t)(ks * 16 + ft) * 512 + (size_t)l * 8)) = v;
}

// ---------------- conv tile: 512 threads = 8 waves, 4M x 2N wave grid ----------------
// Block = 256f x TT t (TT = NFRAG*32). X rows [t0, t0+TT+1) staged once in LDS (bf16);
// the whole K=608 loop runs from LDS. W streamed from L2 in swizzled fragment tiles.
// Wave w: wm = w&3 owns f [wm*64, wm*64+64) (4 m-frags); wn = w>>2 owns t-half (NFRAG n-frags).
// NORM=true : grid = batches, t0 = 0, in-block unit-normalize -> out[batch][256].
// NORM=false: grid = nMain*2 + 2; b < nMain*2: batch = b>>1, chunk c = b&1; else doc branch
//             (X2/W2/bias2), batch-slot nMain, c = b - nMain*2. Partials -> out[(batch*2+c)*256+f].
template<int NFRAG, bool NORM>
__global__ __launch_bounds__(512, 4)
void conv_tile(const float* __restrict__ X, const bf16_t* __restrict__ Wswz,
               const float* __restrict__ bias, float* __restrict__ out,
               int L, int T,
               const float* __restrict__ X2, const bf16_t* __restrict__ W2,
               const float* __restrict__ bias2, int nMain) {
    constexpr int TT    = NFRAG * 32;
    constexpr int NROWS = TT + 1;
    __shared__ bf16_t Xlds[NROWS * 300 + 8];
    __shared__ float  feat2[512];
    __shared__ float  red[8];

    const int tid = threadIdx.x;
    const int l   = tid & 63;
    const int w   = tid >> 6;
    const int wm  = w & 3;
    const int wn  = w >> 2;
    const int g   = l >> 4;
    const int l15 = l & 15;

    const float* Xb;
    const bf16_t* Wb;
    const float* bp;
    int slot, t0;
    if constexpr (NORM) {
        Xb = X + (size_t)blockIdx.x * L * 300; Wb = Wswz; bp = bias;
        slot = blockIdx.x; t0 = 0;
    } else {
        int c;
        if ((int)blockIdx.x >= nMain * 2) {          // doc rider
            c = blockIdx.x - nMain * 2;
            Xb = X2; Wb = W2; bp = bias2;
            slot = nMain * 2 + c;
        } else {
            int batch = blockIdx.x >> 1;
            c = blockIdx.x & 1;
            Xb = X + (size_t)batch * L * 300;
            Wb = Wswz; bp = bias;
            slot = batch * 2 + c;
        }
        t0 = c * TT;
    }

    // ---- stage rows [t0, t0+NROWS) of X as bf16 (contiguous; im2col via row overlap) ----
    {
        const int vr  = (L - t0 < NROWS) ? (L - t0) : NROWS;
        const float* src = Xb + (size_t)t0 * 300;
        const int nF4 = vr * 75;
        for (int v = tid; v < nF4; v += 512) {
            float4 fv = *(const float4*)(src + (size_t)v * 4);
            bf16x4 hv = { (bf16_t)fv.x, (bf16_t)fv.y, (bf16_t)fv.z, (bf16_t)fv.w };
            *(bf16x4*)(Xlds + v * 4) = hv;
        }
        bf16x4 z4 = { (bf16_t)0.f, (bf16_t)0.f, (bf16_t)0.f, (bf16_t)0.f };
        for (int v = nF4 + tid; v < NROWS * 75; v += 512)
            *(bf16x4*)(Xlds + v * 4) = z4;
        if (tid < 4) ((unsigned int*)(Xlds + NROWS * 300))[tid] = 0u;   // 16B guard (k=600..607 overrun)
    }

    // A-tile pointer: wave wm's 4 f-tiles at K-step ks live at ((ks*16 + wm*4 + i)*512 + l*8)
    const bf16_t* wa = Wb + ((size_t)(wm * 4) * 512 + (size_t)l * 8);

    // B LDS element offsets per n-frag (k-part added per step)
    int boff[NFRAG];
#pragma unroll
    for (int j = 0; j < NFRAG; j++)
        boff[j] = (wn * NFRAG * 16 + j * 16 + l15) * 300 + g * 8;

    bf16x8 aCur[4], aNxt[4];
#pragma unroll
    for (int i = 0; i < 4; i++) aCur[i] = *(const bf16x8*)(wa + i * 512);

    __syncthreads();

    f32x4 acc[4][NFRAG];
#pragma unroll
    for (int i = 0; i < 4; i++)
#pragma unroll
        for (int j = 0; j < NFRAG; j++)
            acc[i][j] = (f32x4){0.f, 0.f, 0.f, 0.f};

    for (int ks = 0; ks < NKS; ++ks) {
        if (ks + 1 < NKS) {
            const bf16_t* wn_p = wa + (size_t)(ks + 1) * 16 * 512;
#pragma unroll
            for (int i = 0; i < 4; i++) aNxt[i] = *(const bf16x8*)(wn_p + i * 512);
        }
        const int k0 = ks * 32;
        bf16x8 bb[NFRAG];
#pragma unroll
        for (int j = 0; j < NFRAG; j++) {
            bf16x4 lo = *(const bf16x4*)(Xlds + boff[j] + k0);
            bf16x4 hi = *(const bf16x4*)(Xlds + boff[j] + k0 + 4);
            bb[j] = __builtin_shufflevector(lo, hi, 0, 1, 2, 3, 4, 5, 6, 7);
        }
#pragma unroll
        for (int i = 0; i < 4; i++)
#pragma unroll
            for (int j = 0; j < NFRAG; j++)
                acc[i][j] = __builtin_amdgcn_mfma_f32_16x16x32_bf16(aCur[i], bb[j], acc[i][j], 0, 0, 0);
#pragma unroll
        for (int i = 0; i < 4; i++) aCur[i] = aNxt[i];
    }

    // ---- epilogue: relu(C + bias), mask t<T, reduce over t; cross-wn via feat2 ----
#pragma unroll
    for (int i = 0; i < 4; i++) {
#pragma unroll
        for (int r = 0; r < 4; r++) {
            const int row = wm * 64 + i * 16 + g * 4 + r;
            const float bi = bp[row];
            float s = 0.f;
#pragma unroll
            for (int j = 0; j < NFRAG; j++) {
                int t = t0 + wn * NFRAG * 16 + j * 16 + l15;
                float v = acc[i][j][r] + bi;
                v = fmaxf(v, 0.f);
                s += (t < T) ? v : 0.f;
            }
            s += __shfl_xor(s, 1);
            s += __shfl_xor(s, 2);
            s += __shfl_xor(s, 4);
            s += __shfl_xor(s, 8);
            if (l15 == 0) feat2[wn * 256 + row] = s;
        }
    }
    __syncthreads();

    if constexpr (NORM) {
        float v = 0.f, sq = 0.f;
        if (tid < 256) { v = feat2[tid] + feat2[256 + tid]; sq = v * v; }
        sq += __shfl_xor(sq, 1);
        sq += __shfl_xor(sq, 2);
        sq += __shfl_xor(sq, 4);
        sq += __shfl_xor(sq, 8);
        sq += __shfl_xor(sq, 16);
        sq += __shfl_xor(sq, 32);
        if (l == 0) red[w] = sq;
        __syncthreads();
        float tot = red[0] + red[1] + red[2] + red[3];
        if (tid < 256)
            out[(size_t)slot * 256 + tid] = v / sqrtf(tot);
    } else {
        if (tid < 256)
            out[(size_t)slot * 256 + tid] = feat2[tid] + feat2[256 + tid];
    }
}

// ---------------- combine 2 partials + unit-normalize (body + doc) ----------------
__global__ __launch_bounds__(256)
void combine_norm(const float* __restrict__ part, float* __restrict__ neb,
                  float* __restrict__ nmd, int nMain) {
    __shared__ float red[4];
    int bid = blockIdx.x, tid = threadIdx.x;
    float v = part[((size_t)bid * 2 + 0) * 256 + tid]
            + part[((size_t)bid * 2 + 1) * 256 + tid];
    float sq = v * v;
    sq += __shfl_xor(sq, 1);
    sq += __shfl_xor(sq, 2);
    sq += __shfl_xor(sq, 4);
    sq += __shfl_xor(sq, 8);
    sq += __shfl_xor(sq, 16);
    sq += __shfl_xor(sq, 32);
    if ((tid & 63) == 0) red[tid >> 6] = sq;
    __syncthreads();
    float tot = red[0] + red[1] + red[2] + red[3];
    float o = v / sqrtf(tot);
    if (bid >= nMain) nmd[tid] = o;
    else neb[(size_t)bid * 256 + tid] = o;
}

// ---------------- dt/db: dot normalized doc features with net/neb rows ----------------
__global__ __launch_bounds__(256)
void dt_db_kernel(const float* __restrict__ nmd, const float* __restrict__ net,
                  const float* __restrict__ neb, float* __restrict__ dt,
                  float* __restrict__ db) {
    __shared__ float md[256];
    int tid = threadIdx.x;
    md[tid] = nmd[tid];
    __syncthreads();
    int n = blockIdx.x * 256 + tid;
    const float4* tp = (const float4*)(net + (size_t)n * 256);
    const float4* bp = (const float4*)(neb + (size_t)n * 256);
    float dT = 0.f, dB = 0.f;
    for (int i = 0; i < 64; i++) {
        float4 mm = *(const float4*)(md + i * 4);
        float4 tv = tp[i], bv = bp[i];
        dT += mm.x * tv.x + mm.y * tv.y + mm.z * tv.z + mm.w * tv.w;
        dB += mm.x * bv.x + mm.y * bv.y + mm.z * bv.z + mm.w * bv.w;
    }
    dt[n] = dT;
    db[n] = dB;
}

// ---------------- cosines + linear + masked softmax (one block per mention row) ----------------
__global__ __launch_bounds__(256)
void pair_kernel(const float* __restrict__ nms, const float* __restrict__ nmc,
                 const float* __restrict__ net, const float* __restrict__ neb,
                 const float* __restrict__ dt, const float* __restrict__ db,
                 const float* __restrict__ wl, const float* __restrict__ bl,
                 const int* __restrict__ me, float* __restrict__ out) {
    __shared__ float sA[256], sB[256], red[4];
    int tid = threadIdx.x, m = blockIdx.x;
    sA[tid] = nms[(size_t)m * 256 + tid];
    sB[tid] = nmc[(size_t)m * 256 + tid];
    __syncthreads();
    float w0 = wl[0], w1 = wl[1], w2 = wl[2], w3 = wl[3], w4 = wl[4], w5 = wl[5], b = bl[0];

    float dst[4], dct[4], dsb[4], dcb[4];
#pragma unroll
    for (int q = 0; q < 4; q++) { dst[q] = 0.f; dct[q] = 0.f; dsb[q] = 0.f; dcb[q] = 0.f; }

    for (int i = 0; i < 64; i++) {
        float4 a = *(const float4*)(sA + i * 4);
        float4 c = *(const float4*)(sB + i * 4);
#pragma unroll
        for (int q = 0; q < 4; q++) {
            int n = q * 256 + tid;
            float4 tv = *(const float4*)(net + (size_t)n * 256 + i * 4);
            float4 bv = *(const float4*)(neb + (size_t)n * 256 + i * 4);
            dst[q] += a.x * tv.x + a.y * tv.y + a.z * tv.z + a.w * tv.w;
            dct[q] += c.x * tv.x + c.y * tv.y + c.z * tv.z + c.w * tv.w;
            dsb[q] += a.x * bv.x + a.y * bv.y + a.z * bv.z + a.w * bv.w;
            dcb[q] += c.x * bv.x + c.y * bv.y + c.z * bv.z + c.w * bv.w;
        }
    }

    float sc[4], ev[4];
    float esum = 0.f;
#pragma unroll
    for (int q = 0; q < 4; q++) {
        int n = q * 256 + tid;
        float msk = (float)me[(size_t)m * 1024 + n];
        float f_st = dst[q] * 0.5f + 0.5f;
        float f_dt = dt[n] * 0.5f + 0.5f;
        float f_ct = dct[q] * 0.5f + 0.5f;
        float f_sb = dsb[q] * 0.5f + 0.5f;
        float f_db = db[n] * 0.5f + 0.5f;
        float f_cb = dcb[q] * 0.5f + 0.5f;
        float s = f_st * w0 + f_dt * w1 + f_ct * w2 + f_sb * w3 + f_db * w4 + f_cb * w5 + b;
        s = (msk != 0.f) ? s : 0.f;
        sc[q] = s;
        ev[q] = (msk != 0.f) ? expf(s / 0.1f) : 0.f;
        esum += ev[q];
    }
    esum += __shfl_xor(esum, 1);
    esum += __shfl_xor(esum, 2);
    esum += __shfl_xor(esum, 4);
    esum += __shfl_xor(esum, 8);
    esum += __shfl_xor(esum, 16);
    esum += __shfl_xor(esum, 32);
    if ((tid & 63) == 0) red[tid >> 6] = esum;
    __syncthreads();
    float tot = red[0] + red[1] + red[2] + red[3];
#pragma unroll
    for (int q = 0; q < 4; q++) {
        int n = q * 256 + tid;
        out[(size_t)m * 1024 + n] = sc[q];
        out[256 * 1024 + (size_t)m * 1024 + n] = ev[q] / tot;
    }
}

extern "C" void kernel_launch(void* const* d_in, const int* in_sizes, int n_in,
                              void* d_out, int out_size, void* d_ws, size_t ws_size,
                              hipStream_t stream) {
    const float* mention = (const float*)d_in[0];
    const float* context = (const float*)d_in[1];
    const float* doc     = (const float*)d_in[2];
    const float* title   = (const float*)d_in[3];
    const float* body    = (const float*)d_in[4];
    const float* W_ms = (const float*)d_in[5];  const float* b_ms = (const float*)d_in[6];
    const float* W_mc = (const float*)d_in[7];  const float* b_mc = (const float*)d_in[8];
    const float* W_md = (const float*)d_in[9];  const float* b_md = (const float*)d_in[10];
    const float* W_et = (const float*)d_in[11]; const float* b_et = (const float*)d_in[12];
    const float* W_eb = (const float*)d_in[13]; const float* b_eb = (const float*)d_in[14];
    const float* w_local = (const float*)d_in[15];
    const float* b_local = (const float*)d_in[16];
    const int*   me      = (const int*)d_in[17];
    float* out = (float*)d_out;

    char* ws = (char*)d_ws;
    bf16_t* Wp = (bf16_t*)ws;
    size_t off = (size_t)5 * FNUM * KPAD * 2;             // W bf16 swizzled: 1,556,480 B
    float* part = (float*)(ws + off); off += (size_t)1025 * 2 * 256 * 4;   // body+doc partials
    float* nms = (float*)(ws + off); off += 256 * 256 * 4;
    float* nmc = (float*)(ws + off); off += 256 * 256 * 4;
    float* net = (float*)(ws + off); off += 1024 * 256 * 4;
    float* neb = (float*)(ws + off); off += 1024 * 256 * 4;
    float* nmd = (float*)(ws + off); off += 256 * 4;
    float* dt  = (float*)(ws + off); off += 1024 * 4;
    float* db  = (float*)(ws + off); off += 1024 * 4;

    const bf16_t* Wms = Wp + (size_t)0 * FNUM * KPAD;
    const bf16_t* Wmc = Wp + (size_t)1 * FNUM * KPAD;
    const bf16_t* Wmd = Wp + (size_t)2 * FNUM * KPAD;
    const bf16_t* Wet = Wp + (size_t)3 * FNUM * KPAD;
    const bf16_t* Web = Wp + (size_t)4 * FNUM * KPAD;

    prep_w_swz<<<380, 256, 0, stream>>>(W_ms, W_mc, W_md, W_et, W_eb, Wp);

    // body (+doc rider): 1024 batches x 2 chunks of TT=128, + 2 doc chunks
    conv_tile<4, false><<<2050, 512, 0, stream>>>(body, Web, b_eb, part, 200, 199,
                                                  doc, Wmd, b_md, 1024);
    // single-tile normalized branches (TT=32 covers T)
    conv_tile<1, true><<<1024, 512, 0, stream>>>(title,   Wet, b_et, net, 20, 19,
                                                 nullptr, nullptr, nullptr, 1 << 30);
    conv_tile<1, true><<<256,  512, 0, stream>>>(context, Wmc, b_mc, nmc, 20, 19,
                                                 nullptr, nullptr, nullptr, 1 << 30);
    conv_tile<1, true><<<256,  512, 0, stream>>>(mention, Wms, b_ms, nms, 10, 9,
                                                 nullptr, nullptr, nullptr, 1 << 30);

    combine_norm<<<1025, 256, 0, stream>>>(part, neb, nmd, 1024);
    dt_db_kernel<<<4, 256, 0, stream>>>(nmd, net, neb, dt, db);
    pair_kernel<<<256, 256, 0, stream>>>(nms, nmc, net, neb, dt, db, w_local, b_local, me, out);
}